// Round 1
// baseline (80.429 us; speedup 1.0000x reference)
//
#include <hip/hip_runtime.h>
#include <stdint.h>

#define SEQ   2048
#define BITS  256
#define HEADS 8
#define NPOS  4
#define MAXD  8
#define NBPN  12
#define TBLN  4096   // 2^NBPN entries per head
#define TBLW  64     // u64 words per head (4096 bits)

typedef unsigned long long u64;
typedef unsigned int       u32;
typedef unsigned short     u16;

// ---- workspace layout (bytes) ----
// tblbits: HEADS*TBLW u64            @ 0        (4096)
// packed : SEQ*4      u64            @ 4096     (65536)
// Aq     : SEQ*HEADS  u16            @ 69632    (32768)
// Ak     : SEQ*HEADS  u16            @ 102400   (32768)
// Ar     : 9*HEADS    u16            @ 135168   (144)
#define OFF_TBL    0
#define OFF_PACKED 4096
#define OFF_AQ     (4096 + 65536)
#define OFF_AK     (4096 + 65536 + 32768)
#define OFF_AR     (4096 + 65536 + 65536)

__global__ void pack_table_kernel(const float* __restrict__ table,
                                  u64* __restrict__ tblbits) {
    int t = blockIdx.x * blockDim.x + threadIdx.x;   // need HEADS*TBLW = 512
    if (t >= HEADS * TBLW) return;
    const float* p = table + t * 64;                 // h*4096 + word*64 == t*64
    u64 bits = 0;
    #pragma unroll
    for (int b = 0; b < 64; ++b) bits |= (u64)(p[b] != 0.0f) << b;
    tblbits[t] = bits;
}

__global__ void pack_tokens_kernel(const int* __restrict__ tokens,
                                   u64* __restrict__ packed) {
    int t = blockIdx.x * blockDim.x + threadIdx.x;   // SEQ*4 = 8192
    const int* p = tokens + t * 64;                  // s*256 + word*64 == t*64
    u64 bits = 0;
    #pragma unroll
    for (int b = 0; b < 64; ++b) bits |= (u64)(p[b] & 1) << b;
    packed[t] = bits;
}

__global__ void addr_parts_kernel(const int* __restrict__ tokens,
                                  const int* __restrict__ head_idx,
                                  u16* __restrict__ Aq, u16* __restrict__ Ak,
                                  u16* __restrict__ Ar) {
    int t = blockIdx.x * blockDim.x + threadIdx.x;   // SEQ*HEADS = 16384
    int s = t >> 3, h = t & 7;
    const int* hi  = head_idx + h * NBPN;
    const int* tok = tokens + s * BITS;
    int aq = 0, ak = 0;
    #pragma unroll
    for (int k = 0; k < NBPN; ++k) {
        int idx = hi[k];
        if (idx < BITS)            aq += tok[idx] << k;
        else if (idx < 2 * BITS)   ak += tok[idx - BITS] << k;
    }
    Aq[t] = (u16)aq;
    Ak[t] = (u16)ak;
    if (t < (MAXD + 1) * HEADS) {                    // 72 threads also do Ar
        int d = t / HEADS, hh = t % HEADS;
        const int* hi2 = head_idx + hh * NBPN;
        int ar = 0;
        #pragma unroll
        for (int k = 0; k < NBPN; ++k) {
            int idx = hi2[k];
            if (idx >= 2 * BITS) {
                int p = idx - 2 * BITS;              // < NPOS by construction
                ar += ((d >> p) & 1) << k;
            }
        }
        Ar[t] = (u16)ar;
    }
}

__device__ inline u64 shfl_down_u64(u64 x, int o) {
    u32 lo = (u32)x, hi = (u32)(x >> 32);
    lo = __shfl_down(lo, o, 64);
    hi = __shfl_down(hi, o, 64);
    return ((u64)hi << 32) | lo;
}

__global__ __launch_bounds__(256) void row_kernel(
        const u64* __restrict__ tblbits, const u64* __restrict__ packed,
        const u16* __restrict__ Aq, const u16* __restrict__ Ak,
        const u16* __restrict__ Ar, float* __restrict__ out) {

    __shared__ u64 tbl[HEADS * TBLW];        // 4 KB: table bitmasks
    __shared__ u16 aqar[MAXD + 1][HEADS];    // Aq[i]+Ar[d] fused per distance
    __shared__ u64 r_acc[4][4];
    __shared__ int r_inc[4];
    __shared__ u64 r_key[4];
    __shared__ u64 f_acc[4];
    __shared__ int f_inc;
    __shared__ int f_bestj;

    const int i   = blockIdx.x;              // row
    const int tid = threadIdx.x;

    tbl[tid]       = tblbits[tid];
    tbl[tid + 256] = tblbits[tid + 256];
    if (tid < (MAXD + 1) * HEADS) {
        int h = tid % HEADS;
        aqar[tid / HEADS][h] = (u16)(Aq[i * HEADS + h] + Ar[tid]);
    }
    __syncthreads();

    u64 acc0 = 0, acc1 = 0, acc2 = 0, acc3 = 0;
    int inc = 0;
    u64 bestkey = 0;

    for (int j = tid; j <= i; j += 256) {
        int dist = i - j; if (dist > MAXD) dist = MAXD;
        const uint4 akv = *(const uint4*)(Ak + j * HEADS);   // 8×u16, 16B aligned
        u32 wv[4] = { akv.x, akv.y, akv.z, akv.w };
        int votes = 0;
        #pragma unroll
        for (int h = 0; h < 8; ++h) {
            u32 ak_h = (wv[h >> 1] >> ((h & 1) * 16)) & 0xFFFFu;
            u32 addr = (u32)aqar[dist][h] + ak_h;            // < 4096 (disjoint bits)
            votes += (int)((tbl[h * TBLW + (addr >> 6)] >> (addr & 63)) & 1ull);
        }
        int att = (votes >= HEADS / 2) ? 1 : 0;
        u64 m = (u64)0 - (u64)att;
        const u64* pj = packed + j * 4;
        acc0 ^= pj[0] & m; acc1 ^= pj[1] & m;
        acc2 ^= pj[2] & m; acc3 ^= pj[3] & m;
        inc += att;
        // max votes, first (smallest-j) tie-break == np.argmax semantics
        u64 key = ((u64)(votes + 1) << 32) | (u64)(0x7FFFFFFF - j);
        if (key > bestkey) bestkey = key;
    }

    #pragma unroll
    for (int o = 32; o > 0; o >>= 1) {
        acc0 ^= shfl_down_u64(acc0, o);
        acc1 ^= shfl_down_u64(acc1, o);
        acc2 ^= shfl_down_u64(acc2, o);
        acc3 ^= shfl_down_u64(acc3, o);
        inc  += __shfl_down(inc, o, 64);
        u64 k2 = shfl_down_u64(bestkey, o);
        if (k2 > bestkey) bestkey = k2;
    }
    int wave = tid >> 6;
    if ((tid & 63) == 0) {
        r_acc[wave][0] = acc0; r_acc[wave][1] = acc1;
        r_acc[wave][2] = acc2; r_acc[wave][3] = acc3;
        r_inc[wave] = inc; r_key[wave] = bestkey;
    }
    __syncthreads();
    if (tid == 0) {
        u64 a0 = 0, a1 = 0, a2 = 0, a3 = 0, bk = 0; int ic = 0;
        #pragma unroll
        for (int w = 0; w < 4; ++w) {
            a0 ^= r_acc[w][0]; a1 ^= r_acc[w][1];
            a2 ^= r_acc[w][2]; a3 ^= r_acc[w][3];
            ic += r_inc[w];
            if (r_key[w] > bk) bk = r_key[w];
        }
        f_acc[0] = a0; f_acc[1] = a1; f_acc[2] = a2; f_acc[3] = a3;
        f_inc = ic;
        f_bestj = 0x7FFFFFFF - (int)(bk & 0xFFFFFFFFu);
    }
    __syncthreads();

    int b = tid;                       // 256 threads == 256 output bits
    u64 wordv = (f_inc > 0) ? f_acc[b >> 6]
                            : packed[f_bestj * 4 + (b >> 6)];
    out[i * BITS + b] = (float)((wordv >> (b & 63)) & 1ull);
}

extern "C" void kernel_launch(void* const* d_in, const int* in_sizes, int n_in,
                              void* d_out, int out_size, void* d_ws, size_t ws_size,
                              hipStream_t stream) {
    const int*   tokens   = (const int*)d_in[0];
    const int*   head_idx = (const int*)d_in[1];
    const float* table    = (const float*)d_in[2];
    float*       out      = (float*)d_out;
    char*        ws       = (char*)d_ws;

    u64* tblbits = (u64*)(ws + OFF_TBL);
    u64* packed  = (u64*)(ws + OFF_PACKED);
    u16* Aq      = (u16*)(ws + OFF_AQ);
    u16* Ak      = (u16*)(ws + OFF_AK);
    u16* Ar      = (u16*)(ws + OFF_AR);

    pack_table_kernel <<<2,  256, 0, stream>>>(table, tblbits);
    pack_tokens_kernel<<<32, 256, 0, stream>>>(tokens, packed);
    addr_parts_kernel <<<64, 256, 0, stream>>>(tokens, head_idx, Aq, Ak, Ar);
    row_kernel        <<<SEQ, 256, 0, stream>>>(tblbits, packed, Aq, Ak, Ar, out);
}

// Round 2
// 76.427 us; speedup vs baseline: 1.0524x; 1.0524x over previous
//
#include <hip/hip_runtime.h>
#include <stdint.h>

#define SEQ   2048
#define BITS  256
#define HEADS 8
#define NPOS  4
#define MAXD  8
#define NBPN  12

typedef unsigned long long u64;
typedef unsigned int       u32;
typedef unsigned short     u16;

// ---- workspace layout (bytes) ----
#define OFF_TBL    0                         // HEADS*64 u64   (4096 B)
#define OFF_PACKED 4096                      // SEQ*4 u64      (65536 B)
#define OFF_AQ     (4096 + 65536)            // SEQ*HEADS u16  (32768 B)
#define OFF_AK     (4096 + 65536 + 32768)    // SEQ*HEADS u16  (32768 B)
#define OFF_AR     (4096 + 65536 + 65536)    // 9*HEADS u16    (144 B)

// One fused prep kernel. Block ranges:
//   [0, 2048)        : pack tokens via ballot   (SEQ*BITS = 524288 bits)
//   [2048, 2176)     : pack table via ballot    (HEADS*4096 = 32768 bits)
//   [2176, 2240)     : Aq/Ak/Ar address parts   (SEQ*HEADS = 16384 entries)
__global__ __launch_bounds__(256) void prep_kernel(
        const int* __restrict__ tokens, const int* __restrict__ head_idx,
        const float* __restrict__ table,
        u64* __restrict__ tblbits, u64* __restrict__ packed,
        u16* __restrict__ Aq, u16* __restrict__ Ak, u16* __restrict__ Ar) {
    const int bid = blockIdx.x, tid = threadIdx.x;
    if (bid < 2048) {
        int t = bid * 256 + tid;                 // bit index into tokens
        u64 m = __ballot(tokens[t] & 1);
        if ((tid & 63) == 0) packed[t >> 6] = m;
    } else if (bid < 2048 + 128) {
        int t = (bid - 2048) * 256 + tid;        // bit index into table
        u64 m = __ballot(table[t] != 0.0f);
        if ((tid & 63) == 0) tblbits[t >> 6] = m;
    } else {
        int t = (bid - 2176) * 256 + tid;        // 0..16383
        int s = t >> 3, h = t & 7;
        const int* hi  = head_idx + h * NBPN;
        const int* tok = tokens + s * BITS;
        int aq = 0, ak = 0;
        #pragma unroll
        for (int k = 0; k < NBPN; ++k) {
            int idx = hi[k];
            if (idx < BITS)          aq += tok[idx] << k;
            else if (idx < 2 * BITS) ak += tok[idx - BITS] << k;
        }
        Aq[t] = (u16)aq;
        Ak[t] = (u16)ak;
        if (t < (MAXD + 1) * HEADS) {            // 72 threads also fill Ar
            int d = t / HEADS, hh = t % HEADS;
            const int* hi2 = head_idx + hh * NBPN;
            int ar = 0;
            #pragma unroll
            for (int k = 0; k < NBPN; ++k) {
                int idx = hi2[k];
                if (idx >= 2 * BITS) ar += ((d >> (idx - 2 * BITS)) & 1) << k;
            }
            Ar[t] = (u16)ar;
        }
    }
}

__device__ inline u64 shfl_down_u64(u64 x, int o) {
    u32 lo = (u32)x, hi = (u32)(x >> 32);
    lo = __shfl_down(lo, o, 64);
    hi = __shfl_down(hi, o, 64);
    return ((u64)hi << 32) | lo;
}

// One row per block, 2 waves per row (128 threads). 2048 blocks -> 8 blocks/CU
// = 16 waves/CU; LDS-gather ILP of 8 per pair covers the ~120-cyc LDS latency.
__global__ __launch_bounds__(128) void row_kernel(
        const u64* __restrict__ tblbits, const u64* __restrict__ packed,
        const u16* __restrict__ Aq, const u16* __restrict__ Ak,
        const u16* __restrict__ Ar, float* __restrict__ out) {

    __shared__ u32 tbl[HEADS * 128];       // 4 KB, u32 words: 1 bank/lookup
    __shared__ u16 aqar[MAXD + 1][HEADS];
    __shared__ u64 p_acc[2][4];
    __shared__ int p_inc[2];
    __shared__ u64 p_key[2];

    const int i   = blockIdx.x;
    const int tid = threadIdx.x;

    const u32* tb32 = (const u32*)tblbits; // little-endian: u32 idx = addr>>5
    #pragma unroll
    for (int w = 0; w < 8; ++w) tbl[tid + w * 128] = tb32[tid + w * 128];
    if (tid < (MAXD + 1) * HEADS) {
        int h = tid & 7;
        aqar[tid >> 3][h] = (u16)(Aq[i * HEADS + h] + Ar[tid]);
    }
    __syncthreads();

    u32 a8[8];                             // dist>=8 bases in registers
    #pragma unroll
    for (int h = 0; h < 8; ++h) a8[h] = aqar[MAXD][h];

    u64 acc0 = 0, acc1 = 0, acc2 = 0, acc3 = 0;
    int inc = 0;
    u64 bestkey = 0;

    for (int j = tid; j <= i; j += 128) {
        int dist = i - j;
        const uint4 akv = *(const uint4*)(Ak + j * HEADS);  // 8xu16, 16B
        int votes = 0;
        if (__any(dist < MAXD)) {          // only the diagonal-adjacent iter
            #pragma unroll
            for (int h = 0; h < 8; ++h) {
                u32 ak_h = ((&akv.x)[h >> 1] >> ((h & 1) * 16)) & 0xFFFFu;
                u32 base = (dist >= MAXD) ? a8[h] : (u32)aqar[dist][h];
                u32 addr = base + ak_h;    // < 4096 (disjoint bit masks)
                votes += (int)((tbl[(h << 7) + (addr >> 5)] >> (addr & 31)) & 1u);
            }
        } else {
            #pragma unroll
            for (int h = 0; h < 8; ++h) {
                u32 ak_h = ((&akv.x)[h >> 1] >> ((h & 1) * 16)) & 0xFFFFu;
                u32 addr = a8[h] + ak_h;
                votes += (int)((tbl[(h << 7) + (addr >> 5)] >> (addr & 31)) & 1u);
            }
        }
        int att = (votes >= HEADS / 2) ? 1 : 0;
        u64 m = (u64)0 - (u64)att;
        const ulonglong2* pj = (const ulonglong2*)(packed + j * 4);
        ulonglong2 pA = pj[0], pB = pj[1];
        acc0 ^= pA.x & m; acc1 ^= pA.y & m;
        acc2 ^= pB.x & m; acc3 ^= pB.y & m;
        inc += att;
        // max votes, first (smallest-j) tie-break == np.argmax semantics
        u64 key = ((u64)(votes + 1) << 32) | (u64)(0x7FFFFFFF - j);
        if (key > bestkey) bestkey = key;
    }

    #pragma unroll
    for (int o = 32; o > 0; o >>= 1) {
        acc0 ^= shfl_down_u64(acc0, o);
        acc1 ^= shfl_down_u64(acc1, o);
        acc2 ^= shfl_down_u64(acc2, o);
        acc3 ^= shfl_down_u64(acc3, o);
        inc  += __shfl_down(inc, o, 64);
        u64 k2 = shfl_down_u64(bestkey, o);
        if (k2 > bestkey) bestkey = k2;
    }
    int wave = tid >> 6;
    if ((tid & 63) == 0) {
        p_acc[wave][0] = acc0; p_acc[wave][1] = acc1;
        p_acc[wave][2] = acc2; p_acc[wave][3] = acc3;
        p_inc[wave] = inc; p_key[wave] = bestkey;
    }
    __syncthreads();

    // every thread combines the two wave partials in registers (no 3rd barrier)
    u64 f0 = p_acc[0][0] ^ p_acc[1][0];
    u64 f1 = p_acc[0][1] ^ p_acc[1][1];
    u64 f2 = p_acc[0][2] ^ p_acc[1][2];
    u64 f3 = p_acc[0][3] ^ p_acc[1][3];
    int finc = p_inc[0] + p_inc[1];
    u64 fk = (p_key[0] > p_key[1]) ? p_key[0] : p_key[1];

    // 2 output bits per thread -> float2 coalesced store
    int b0  = tid * 2;
    int wsel = tid >> 5;                   // which u64 word
    u64 word;
    if (finc > 0) {
        word = (wsel < 2) ? (wsel == 0 ? f0 : f1) : (wsel == 2 ? f2 : f3);
    } else {
        int bestj = 0x7FFFFFFF - (int)(fk & 0xFFFFFFFFu);
        word = packed[bestj * 4 + wsel];
    }
    int sh = b0 & 63;
    float2 o2 = make_float2((float)((word >> sh) & 1ull),
                            (float)((word >> (sh + 1)) & 1ull));
    *(float2*)(out + i * BITS + b0) = o2;
}

extern "C" void kernel_launch(void* const* d_in, const int* in_sizes, int n_in,
                              void* d_out, int out_size, void* d_ws, size_t ws_size,
                              hipStream_t stream) {
    const int*   tokens   = (const int*)d_in[0];
    const int*   head_idx = (const int*)d_in[1];
    const float* table    = (const float*)d_in[2];
    float*       out      = (float*)d_out;
    char*        ws       = (char*)d_ws;

    u64* tblbits = (u64*)(ws + OFF_TBL);
    u64* packed  = (u64*)(ws + OFF_PACKED);
    u16* Aq      = (u16*)(ws + OFF_AQ);
    u16* Ak      = (u16*)(ws + OFF_AK);
    u16* Ar      = (u16*)(ws + OFF_AR);

    prep_kernel<<<2240, 256, 0, stream>>>(tokens, head_idx, table,
                                          tblbits, packed, Aq, Ak, Ar);
    row_kernel <<<SEQ, 128, 0, stream>>>(tblbits, packed, Aq, Ak, Ar, out);
}